// Round 12
// baseline (133.602 us; speedup 1.0000x reference)
//
#include <hip/hip_runtime.h>
#include <hip/hip_bf16.h>

#define PARTS 16
#define NB 128
#define CH 256
#define SL 64
#define HIDN 64

typedef unsigned short u16;
typedef unsigned int u32;
typedef unsigned short ushort8 __attribute__((ext_vector_type(8)));
typedef unsigned short ushort4v __attribute__((ext_vector_type(4)));
typedef __attribute__((ext_vector_type(8))) short short8v;
typedef __attribute__((ext_vector_type(4))) float f32x4;

__device__ __forceinline__ float bf2f(u16 u) {
  union { unsigned u; float f; } t; t.u = ((unsigned)u) << 16; return t.f;
}
__device__ __forceinline__ u16 f2bf(float f) {
  union { float f; unsigned u; } t; t.f = f;
  unsigned u = t.u;
  u += 0x7FFFu + ((u >> 16) & 1u);
  return (u16)(u >> 16);
}
// packed pair convert: low16 = bf16(a), high16 = bf16(b) -> v_cvt_pk_bf16_f32
__device__ __forceinline__ unsigned pk2bf(float a, float b) {
  float2 f; f.x = a; f.y = b;
  union { __hip_bfloat162 h; unsigned u; } cv;
  cv.h = __float22bfloat162_rn(f);
  return cv.u;
}

// ===================== weight conversion prepass (single launch) =====================
// Region offsets in wsb (bf16 elems): W1A @0, W3A @786432, W1B @1572864,
// W3B @1835008. Tap tensors: out[(p*3+t)*16384 + xid] = in[(p*16384+xid)*3+t].
__global__ void cvt_all(const float* __restrict__ w1a, const float* __restrict__ w3a,
                        const float* __restrict__ w1b, const float* __restrict__ w3b,
                        u16* __restrict__ out) {
  const int b = blockIdx.x;
  const int tid = threadIdx.x;
  if (b < 3072) {                      // three tap tensors, 1024 blocks each
    const int reg = b >> 10;           // 0=W1A 1=W3A 2=W3B
    const int i = (b & 1023) * 256 + tid;   // p*16384 + xid
    const int p = i >> 14, xid = i & 16383;
    const float* src = (reg == 0 ? w1a : reg == 1 ? w3a : w3b) + (size_t)i * 3;
    const size_t base = (reg == 0) ? 0 : (reg == 1) ? 786432 : 1835008;
    #pragma unroll
    for (int t = 0; t < 3; ++t)
      out[base + (size_t)(p * 3 + t) * 16384 + xid] = f2bf(src[t]);
  } else {                             // W1B passthrough: 262144 elems
    const int i = (b - 3072) * 256 + tid;
    out[1572864 + i] = f2bf(w1b[i]);
  }
}

// ===================== MFMA main kernel =====================
// r11 structure (best: 118.9us bench / 140.4us rocprof). r12 delta: phase-A
// ks loop FULLY unrolled — r11 diagnosis: latency-bound with all pipes idle;
// unroll-2 limited VMEM prefetch depth to ~2 iterations, so L2 weight-load
// latency recurs ~4x in the dominant phase. Full unroll lets the scheduler
// hoist loads into the 44-VGPR headroom below the 128 cap.
//  XT[r][c]: r = s+2, rows 0..67, 256 cols, XOR-swizzled, pad rows 0,1,66,67.
//  HT[r][h]: r = s+1, rows 0..65, 64 cols, pad rows 0,65.
#define XROWS 68
#define HROWS 66

__device__ __forceinline__ int xsw(int r, int c) { return (r * 256 + c) ^ ((r & 7) << 3); }
__device__ __forceinline__ int hsw(int r, int c) { return (r * 64 + c) ^ ((r & 7) << 3); }

// __launch_bounds__(256, 2): effective VGPR cap = 256/arg2 = 128 (calibrated
// r4-r8: (512,6)->40, (512,3)->80, (256,4)->64, (256,2)->128, no spill).
__global__ __launch_bounds__(256, 2) void tfa_mfma(
    const float* __restrict__ x,
    const u16* __restrict__ wsb,
    float* __restrict__ out)
{
  const u16* W1A = wsb;                 // [p][t][h][c]  786432
  const u16* W3A = wsb + 786432;        // [p][t][h][c]  786432
  const u16* W1B = wsb + 1572864;       // [p][c][h]     262144
  const u16* W3B = wsb + 1835008;       // [p][t][c][h]  786432

  __shared__ __attribute__((aligned(16))) u16 xt[XROWS * 256];   // 34816 B
  __shared__ __attribute__((aligned(16))) u16 ht1[HROWS * 64];   //  8448 B
  __shared__ __attribute__((aligned(16))) u16 ht3[HROWS * 64];   //  8448 B

  const int tid = threadIdx.x;
  const int bid = blockIdx.x;          // p*NB + n
  const int p = bid >> 7;
  const int lane = tid & 63;
  const int w = tid >> 6;              // wave id 0..3

  // ---- zero the pad rows ----
  if (tid < 128) {
    const int rr4 = (tid >> 5);
    const int r = (rr4 == 0) ? 0 : (rr4 == 1) ? 1 : (rr4 == 2) ? 66 : 67;
    const int c = (tid & 31) * 8;
    *(ushort8*)&xt[xsw(r, c)] = (ushort8)0;
  } else if (tid < 160) {
    const int t2 = tid - 128;          // bit4=buffer, bit3=row, bits0-2=col chunk
    const int r = (t2 & 8) ? 65 : 0;
    const int c = (t2 & 7) * 8;
    u16* b = (t2 & 16) ? ht3 : ht1;
    *(ushort8*)&b[hsw(r, c)] = (ushort8)0;
  }

  // ---- stage x -> XT (transposed, bf16, swizzled); lane = s, wave: 64 c ----
  {
    const float* xb = x + (size_t)bid * (CH * SL);
    const int s = lane;
    const int r = s + 2;
    #pragma unroll
    for (int j = 0; j < 8; ++j) {
      const int c0 = w * 64 + j * 8;
      union { ushort8 v; unsigned u[4]; } ov;
      #pragma unroll
      for (int k = 0; k < 4; ++k) {
        const float fa = xb[(c0 + 2 * k) * 64 + s];
        const float fb = xb[(c0 + 2 * k + 1) * 64 + s];
        ov.u[k] = pk2bf(fa, fb);
      }
      *(ushort8*)&xt[xsw(r, c0)] = ov.v;
    }
  }
  __syncthreads();

  // ---- phase A: conv1 both branches; wave owns h-tile [w*16, w*16+16) ----
  // 8 independent accumulator chains; ks loop fully unrolled for prefetch depth.
  {
    const int hm = lane & 15;
    const int kg = lane >> 4;
    const int h = w * 16 + hm;
    f32x4 acc1[4], acc3[4];
    #pragma unroll
    for (int nt = 0; nt < 4; ++nt) { acc1[nt] = (f32x4)0.f; acc3[nt] = (f32x4)0.f; }

    #pragma unroll
    for (int ks = 0; ks < 8; ++ks) {
      const int kc = ks * 32 + kg * 8;
      short8v a1[3], a3[3];
      #pragma unroll
      for (int t = 0; t < 3; ++t) {
        a1[t] = *(const short8v*)&W1A[(size_t)((p * 3 + t) * 64 + h) * 256 + kc];
        a3[t] = *(const short8v*)&W3A[(size_t)((p * 3 + t) * 64 + h) * 256 + kc];
      }
      #pragma unroll
      for (int nt = 0; nt < 4; ++nt) {
        const int s = nt * 16 + hm;    // B-frag n index
        #pragma unroll
        for (int t = 0; t < 3; ++t) {
          const int r = s + t + 1;     // tap s+(t-1) -> XT row; pads give zeros
          const short8v b = *(const short8v*)&xt[xsw(r, kc)];
          acc1[nt] = __builtin_amdgcn_mfma_f32_16x16x32_bf16(a1[t], b, acc1[nt], 0, 0, 0);
          acc3[nt] = __builtin_amdgcn_mfma_f32_16x16x32_bf16(a3[t], b, acc3[nt], 0, 0, 0);
        }
      }
    }

    // epilogue: LeakyReLU -> bf16 -> HT[s][h]
    const int hc = w * 16 + kg * 4;
    #pragma unroll
    for (int nt = 0; nt < 4; ++nt) {
      const int s = nt * 16 + hm;
      const int r = s + 1;
      float v1[4], v3[4];
      #pragma unroll
      for (int q = 0; q < 4; ++q) {
        const float a = acc1[nt][q]; v1[q] = a >= 0.f ? a : 0.01f * a;
        const float bq = acc3[nt][q]; v3[q] = bq >= 0.f ? bq : 0.01f * bq;
      }
      union { ushort4v v; u32 u[2]; } o1, o3;
      o1.u[0] = pk2bf(v1[0], v1[1]); o1.u[1] = pk2bf(v1[2], v1[3]);
      o3.u[0] = pk2bf(v3[0], v3[1]); o3.u[1] = pk2bf(v3[2], v3[3]);
      *(ushort4v*)&ht1[hsw(r, hc)] = o1.v;
      *(ushort4v*)&ht3[hsw(r, hc)] = o3.v;
    }
  }
  __syncthreads();

  // ---- phase B: conv2 both branches + gates + pools + max over s ----
  // wave w owns c in [w*64, w*64+64), in mt-halves. Separate B1/B3 accs
  // (r11) so g1p's trans ops can overlap B3's MFMAs.
  {
    const int cm = lane & 15;
    const int kg = lane >> 4;

    #pragma unroll
    for (int half = 0; half < 2; ++half) {
      const int mtb = half * 2;
      f32x4 acc1b[2][4], acc3b[2][4];
      #pragma unroll
      for (int mt = 0; mt < 2; ++mt)
        #pragma unroll
        for (int nt = 0; nt < 4; ++nt) { acc1b[mt][nt] = (f32x4)0.f; acc3b[mt][nt] = (f32x4)0.f; }

      // branch 1: K=64h, k1 conv (no shift)
      #pragma unroll
      for (int ks = 0; ks < 2; ++ks) {
        const int kh = ks * 32 + kg * 8;
        short8v a[2];
        #pragma unroll
        for (int mt = 0; mt < 2; ++mt) {
          const int c = w * 64 + (mtb + mt) * 16 + cm;
          a[mt] = *(const short8v*)&W1B[((size_t)p * 256 + c) * 64 + kh];
        }
        #pragma unroll
        for (int nt = 0; nt < 4; ++nt) {
          const int s = nt * 16 + cm;
          const short8v b = *(const short8v*)&ht1[hsw(s + 1, kh)];
          #pragma unroll
          for (int mt = 0; mt < 2; ++mt)
            acc1b[mt][nt] = __builtin_amdgcn_mfma_f32_16x16x32_bf16(a[mt], b, acc1b[mt][nt], 0, 0, 0);
        }
      }

      // gates g1 = sigmoid(L1), packed bf16 pairs (independent of acc3b)
      unsigned g1p[2][4][2];
      #pragma unroll
      for (int mt = 0; mt < 2; ++mt)
        #pragma unroll
        for (int nt = 0; nt < 4; ++nt) {
          #pragma unroll
          for (int j = 0; j < 2; ++j) {
            const float ga = 1.f / (1.f + __expf(-acc1b[mt][nt][2 * j]));
            const float gb = 1.f / (1.f + __expf(-acc1b[mt][nt][2 * j + 1]));
            g1p[mt][nt][j] = pk2bf(ga, gb);
          }
        }

      // branch 3: 3 tap-GEMMs, K=64h each, B rows shifted (pads give zeros)
      #pragma unroll
      for (int ks = 0; ks < 2; ++ks) {
        const int kh = ks * 32 + kg * 8;
        #pragma unroll
        for (int t = 0; t < 3; ++t) {
          short8v a[2];
          #pragma unroll
          for (int mt = 0; mt < 2; ++mt) {
            const int c = w * 64 + (mtb + mt) * 16 + cm;
            a[mt] = *(const short8v*)&W3B[(size_t)((p * 3 + t) * 256 + c) * 64 + kh];
          }
          #pragma unroll
          for (int nt = 0; nt < 4; ++nt) {
            const int s = nt * 16 + cm;
            const short8v b = *(const short8v*)&ht3[hsw(s + t, kh)];  // s+(t-1)+1
            #pragma unroll
            for (int mt = 0; mt < 2; ++mt)
              acc3b[mt][nt] = __builtin_amdgcn_mfma_f32_16x16x32_bf16(a[mt], b, acc3b[mt][nt], 0, 0, 0);
          }
        }
      }

      // epilogue: pools from XT, gates, fused max over s
      #pragma unroll
      for (int mt = 0; mt < 2; ++mt) {
        const int c4 = w * 64 + (mtb + mt) * 16 + kg * 4;   // 4 consecutive c
        float fmx0 = -INFINITY, fmx1 = -INFINITY, fmx2 = -INFINITY, fmx3 = -INFINITY;
        #pragma unroll
        for (int nt = 0; nt < 4; ++nt) {
          const int s = nt * 16 + cm;               // D col: global s
          const ushort4v vm2 = *(const ushort4v*)&xt[xsw(s,     c4)];
          const ushort4v vm1 = *(const ushort4v*)&xt[xsw(s + 1, c4)];
          const ushort4v v0  = *(const ushort4v*)&xt[xsw(s + 2, c4)];
          const ushort4v vp1 = *(const ushort4v*)&xt[xsw(s + 3, c4)];
          const ushort4v vp2 = *(const ushort4v*)&xt[xsw(s + 4, c4)];
          const float NI = -INFINITY;
          float ft[4];
          #pragma unroll
          for (int q = 0; q < 4; ++q) {
            const float xm2 = bf2f(vm2[q]), xm1 = bf2f(vm1[q]), x0 = bf2f(v0[q]);
            const float xp1 = bf2f(vp1[q]), xp2 = bf2f(vp2[q]);
            const float mx3 = fmaxf(x0, fmaxf(s >= 1 ? xm1 : NI, s <= 62 ? xp1 : NI));
            const float mx5 = fmaxf(mx3, fmaxf(s >= 2 ? xm2 : NI, s <= 61 ? xp2 : NI));
            const float sum3 = xm1 + x0 + xp1;           // pads are zero
            const float av3 = sum3 * (1.f / 3.f);
            const float av5 = (sum3 + xm2 + xp2) * 0.2f; // sum3 reuse
            const float g1 = bf2f((u16)(g1p[mt][nt][q >> 1] >> ((q & 1) * 16)));
            const float g3 = 1.f / (1.f + __expf(-acc3b[mt][nt][q]));
            ft[q] = (av3 + mx3) * g1 + (av5 + mx5) * g3;
          }
          fmx0 = fmaxf(fmx0, ft[0]); fmx1 = fmaxf(fmx1, ft[1]);
          fmx2 = fmaxf(fmx2, ft[2]); fmx3 = fmaxf(fmx3, ft[3]);
        }
        // reduce max across the 16 lanes of each row-group
        #pragma unroll
        for (int off = 1; off < 16; off <<= 1) {
          fmx0 = fmaxf(fmx0, __shfl_xor(fmx0, off));
          fmx1 = fmaxf(fmx1, __shfl_xor(fmx1, off));
          fmx2 = fmaxf(fmx2, __shfl_xor(fmx2, off));
          fmx3 = fmaxf(fmx3, __shfl_xor(fmx3, off));
        }
        if (cm == 0) {
          float4 o; o.x = fmx0; o.y = fmx1; o.z = fmx2; o.w = fmx3;
          *(float4*)&out[(size_t)bid * 256 + c4] = o;
        }
      }
    }
  }
}

// ===================== fallback vector kernel (round-1, correct) =====================
#define XROW 72
#define HROW 72

__global__ __launch_bounds__(256, 2) void tfa_kernel(
    const float* __restrict__ x,
    const float* __restrict__ w1a,
    const float* __restrict__ w1b,
    const float* __restrict__ w3a,
    const float* __restrict__ w3b,
    float* __restrict__ out)
{
  __shared__ __attribute__((aligned(16))) u16 x_s[8 + CH * XROW];
  __shared__ __attribute__((aligned(16))) u16 h1_s[8 + HIDN * HROW];
  __shared__ __attribute__((aligned(16))) u16 h3_s[8 + HIDN * HROW];

  const int tid = threadIdx.x;
  const int bid = blockIdx.x;
  const int p = bid >> 7;

  {
    const ushort8 z = {0, 0, 0, 0, 0, 0, 0, 0};
    for (int i = tid; i < 257; i += 256) {
      u16* dst = (i == 0) ? &x_s[0] : &x_s[8 + (i - 1) * XROW + 64];
      *(ushort8*)dst = z;
    }
    if (tid < 65) {
      u16* d1 = (tid == 0) ? &h1_s[0] : &h1_s[8 + (tid - 1) * HROW + 64];
      *(ushort8*)d1 = z;
      u16* d3 = (tid == 0) ? &h3_s[0] : &h3_s[8 + (tid - 1) * HROW + 64];
      *(ushort8*)d3 = z;
    }
  }

  const float* xblk = x + (size_t)bid * (CH * SL);
  #pragma unroll
  for (int j = 0; j < 16; ++j) {
    const int g = tid + 256 * j;
    const float4 v = ((const float4*)xblk)[g];
    const int c = g >> 4, s4 = g & 15;
    ushort4v o;
    o[0] = f2bf(v.x); o[1] = f2bf(v.y); o[2] = f2bf(v.z); o[3] = f2bf(v.w);
    *(ushort4v*)&x_s[8 + c * XROW + s4 * 4] = o;
  }
  __syncthreads();

  {
    const int h = tid >> 2;
    const int sg = tid & 3;
    const int sb = sg << 4;
    float acc1[16], acc3[16];
    #pragma unroll
    for (int i = 0; i < 16; ++i) { acc1[i] = 0.f; acc3[i] = 0.f; }

    const float* w1a_p = w1a + ((size_t)p * HIDN + h) * (CH * 3);
    const float* w3a_p = w3a + ((size_t)p * HIDN + h) * (CH * 3);

    for (int c4 = 0; c4 < CH; c4 += 4) {
      const float4 a0v = *(const float4*)&w1a_p[c4 * 3];
      const float4 a1v = *(const float4*)&w1a_p[c4 * 3 + 4];
      const float4 a2v = *(const float4*)&w1a_p[c4 * 3 + 8];
      const float4 b0v = *(const float4*)&w3a_p[c4 * 3];
      const float4 b1v = *(const float4*)&w3a_p[c4 * 3 + 4];
      const float4 b2v = *(const float4*)&w3a_p[c4 * 3 + 8];
      float wa[12], wb[12];
      wa[0]=a0v.x; wa[1]=a0v.y; wa[2]=a0v.z; wa[3]=a0v.w;
      wa[4]=a1v.x; wa[5]=a1v.y; wa[6]=a1v.z; wa[7]=a1v.w;
      wa[8]=a2v.x; wa[9]=a2v.y; wa[10]=a2v.z; wa[11]=a2v.w;
      wb[0]=b0v.x; wb[1]=b0v.y; wb[2]=b0v.z; wb[3]=b0v.w;
      wb[4]=b1v.x; wb[5]=b1v.y; wb[6]=b1v.z; wb[7]=b1v.w;
      wb[8]=b2v.x; wb[9]=b2v.y; wb[10]=b2v.z; wb[11]=b2v.w;

      #pragma unroll
      for (int cc = 0; cc < 4; ++cc) {
        const int c = c4 + cc;
        const ushort8 w0v = *(const ushort8*)&x_s[c * XROW + sb];
        const ushort8 w1v = *(const ushort8*)&x_s[c * XROW + sb + 8];
        const ushort8 w2v = *(const ushort8*)&x_s[c * XROW + sb + 16];
        const ushort8 w3v = *(const ushort8*)&x_s[c * XROW + sb + 24];
        float xf[19];
        xf[0] = bf2f(w0v[7]);
        #pragma unroll
        for (int d = 0; d < 8; ++d) xf[1 + d] = bf2f(w1v[d]);
        #pragma unroll
        for (int d = 0; d < 8; ++d) xf[9 + d] = bf2f(w2v[d]);
        xf[17] = bf2f(w3v[0]);
        xf[18] = bf2f(w3v[1]);

        const float a0 = wa[cc * 3], a1 = wa[cc * 3 + 1], a2 = wa[cc * 3 + 2];
        const float b0 = wb[cc * 3], b1 = wb[cc * 3 + 1], b2 = wb[cc * 3 + 2];
        #pragma unroll
        for (int i = 0; i < 16; ++i) {
          const float xm = xf[i], x0 = xf[i + 1], xp = xf[i + 2];
          acc1[i] = fmaf(a0, xm, fmaf(a1, x0, fmaf(a2, xp, acc1[i])));
          acc3[i] = fmaf(b0, xm, fmaf(b1, x0, fmaf(b2, xp, acc3[i])));
        }
      }
    }

    ushort8 o1a, o1b, o3a, o3b;
    #pragma unroll
    for (int i = 0; i < 8; ++i) {
      float v1 = acc1[i];     v1 = v1 >= 0.f ? v1 : 0.01f * v1;
      float v3 = acc3[i];     v3 = v3 >= 0.f ? v3 : 0.01f * v3;
      o1a[i] = f2bf(v1); o3a[i] = f2bf(v3);
      float u1 = acc1[i + 8]; u1 = u1 >= 0.f ? u1 : 0.01f * u1;
      float u3 = acc3[i + 8]; u3 = u3 >= 0.f ? u3 : 0.01f * u3;
      o1b[i] = f2bf(u1); o3b[i] = f2bf(u3);
    }
    *(ushort8*)&h1_s[8 + h * HROW + sb]     = o1a;
    *(ushort8*)&h1_s[8 + h * HROW + sb + 8] = o1b;
    *(ushort8*)&h3_s[8 + h * HROW + sb]     = o3a;
    *(ushort8*)&h3_s[8 + h * HROW + sb + 8] = o3b;
  }
  __syncthreads();

  {
    const int lane = tid & 63;
    const int wid = __builtin_amdgcn_readfirstlane(tid >> 6);
    const int s = lane;
    const float* w1b_p = w1b + (size_t)p * (CH * HIDN);
    const float* w3b_p = w3b + (size_t)p * (CH * HIDN * 3);
    float* outp = out + (size_t)bid * CH;

    for (int q = 0; q < 16; ++q) {
      const int c0 = wid * 64 + q * 4;
      float l1[4] = {0.f, 0.f, 0.f, 0.f};
      float l3[4] = {0.f, 0.f, 0.f, 0.f};

      for (int h4 = 0; h4 < HIDN; h4 += 4) {
        float h1v[4], h3a[4], h3b[4], h3c[4];
        #pragma unroll
        for (int u = 0; u < 4; ++u) {
          const int hh = h4 + u;
          h1v[u] = bf2f(h1_s[8 + hh * HROW + s]);
          h3a[u] = bf2f(h3_s[7 + hh * HROW + s]);
          h3b[u] = bf2f(h3_s[8 + hh * HROW + s]);
          h3c[u] = bf2f(h3_s[9 + hh * HROW + s]);
        }
        #pragma unroll
        for (int j = 0; j < 4; ++j) {
          const int c = c0 + j;
          const float4 wv  = *(const float4*)&w1b_p[c * HIDN + h4];
          const float* w3  = &w3b_p[(size_t)(c * HIDN + h4) * 3];
          const float4 w30 = *(const float4*)w3;
          const float4 w31 = *(const float4*)(w3 + 4);
          const float4 w32 = *(const float4*)(w3 + 8);
          float ww[12];
          ww[0]=w30.x; ww[1]=w30.y; ww[2]=w30.z; ww[3]=w30.w;
          ww[4]=w31.x; ww[5]=w31.y; ww[6]=w31.z; ww[7]=w31.w;
          ww[8]=w32.x; ww[9]=w32.y; ww[10]=w32.z; ww[11]=w32.w;
          l1[j] = fmaf(wv.x, h1v[0], fmaf(wv.y, h1v[1],
                  fmaf(wv.z, h1v[2], fmaf(wv.w, h1v[3], l1[j]))));
          #pragma unroll
          for (int u = 0; u < 4; ++u) {
            l3[j] = fmaf(ww[u * 3], h3a[u],
                    fmaf(ww[u * 3 + 1], h3b[u],
                    fmaf(ww[u * 3 + 2], h3c[u], l3[j])));
          }
        }
      }

      #pragma unroll
      for (int j = 0; j < 4; ++j) {
        const int c = c0 + j;
        const u16* xr = &x_s[8 + c * XROW];
        const float xm2 = bf2f(xr[s - 2]);
        const float xm1 = bf2f(xr[s - 1]);
        const float x0  = bf2f(xr[s]);
        const float xp1 = bf2f(xr[s + 1]);
        const float xp2 = bf2f(xr[s + 2]);
        const float NI = -INFINITY;
        const float mx3 = fmaxf(x0, fmaxf(s >= 1 ? xm1 : NI, s <= 62 ? xp1 : NI));
        const float mx5 = fmaxf(mx3, fmaxf(s >= 2 ? xm2 : NI, s <= 61 ? xp2 : NI));
        const float av3 = (xm1 + x0 + xp1) * (1.f / 3.f);
        const float av5 = (xm2 + xm1 + x0 + xp1 + xp2) * 0.2f;
        const float sg1 = 1.f / (1.f + __expf(-l1[j]));
        const float sg3 = 1.f / (1.f + __expf(-l3[j]));
        float feat = (av3 + mx3) * sg1 + (av5 + mx5) * sg3;
        #pragma unroll
        for (int off = 32; off >= 1; off >>= 1)
          feat = fmaxf(feat, __shfl_xor(feat, off));
        if (lane == 0) outp[c] = feat;
      }
    }
  }
}

extern "C" void kernel_launch(void* const* d_in, const int* in_sizes, int n_in,
                              void* d_out, int out_size, void* d_ws, size_t ws_size,
                              hipStream_t stream) {
  (void)in_sizes; (void)n_in; (void)out_size;
  const float* x   = (const float*)d_in[0];
  const float* w1a = (const float*)d_in[1];
  const float* w1b = (const float*)d_in[2];
  const float* w3a = (const float*)d_in[3];
  const float* w3b = (const float*)d_in[4];
  float* out = (float*)d_out;

  const size_t WS_NEED = 2621440ull * 2ull;  // 5 MB of bf16 weights
  if (ws_size >= WS_NEED) {
    u16* wsb = (u16*)d_ws;
    cvt_all<<<4096, 256, 0, stream>>>(w1a, w3a, w1b, w3b, wsb);
    tfa_mfma<<<PARTS * NB, 256, 0, stream>>>(x, wsb, out);
  } else {
    tfa_kernel<<<PARTS * NB, 256, 0, stream>>>(x, w1a, w1b, w3a, w3b, out);
  }
}

// Round 13
// 118.897 us; speedup vs baseline: 1.1237x; 1.1237x over previous
//
#include <hip/hip_runtime.h>
#include <hip/hip_bf16.h>

#define PARTS 16
#define NB 128
#define CH 256
#define SL 64
#define HIDN 64

typedef unsigned short u16;
typedef unsigned int u32;
typedef unsigned short ushort8 __attribute__((ext_vector_type(8)));
typedef unsigned short ushort4v __attribute__((ext_vector_type(4)));
typedef __attribute__((ext_vector_type(8))) short short8v;
typedef __attribute__((ext_vector_type(4))) float f32x4;

__device__ __forceinline__ float bf2f(u16 u) {
  union { unsigned u; float f; } t; t.u = ((unsigned)u) << 16; return t.f;
}
__device__ __forceinline__ u16 f2bf(float f) {
  union { float f; unsigned u; } t; t.f = f;
  unsigned u = t.u;
  u += 0x7FFFu + ((u >> 16) & 1u);
  return (u16)(u >> 16);
}
// packed pair convert: low16 = bf16(a), high16 = bf16(b) -> v_cvt_pk_bf16_f32
__device__ __forceinline__ unsigned pk2bf(float a, float b) {
  float2 f; f.x = a; f.y = b;
  union { __hip_bfloat162 h; unsigned u; } cv;
  cv.h = __float22bfloat162_rn(f);
  return cv.u;
}

// ===================== weight conversion prepass (single launch) =====================
// Region offsets in wsb (bf16 elems): W1A @0, W3A @786432, W1B @1572864,
// W3B @1835008. Tap tensors: out[(p*3+t)*16384 + xid] = in[(p*16384+xid)*3+t].
__global__ void cvt_all(const float* __restrict__ w1a, const float* __restrict__ w3a,
                        const float* __restrict__ w1b, const float* __restrict__ w3b,
                        u16* __restrict__ out) {
  const int b = blockIdx.x;
  const int tid = threadIdx.x;
  if (b < 3072) {                      // three tap tensors, 1024 blocks each
    const int reg = b >> 10;           // 0=W1A 1=W3A 2=W3B
    const int i = (b & 1023) * 256 + tid;   // p*16384 + xid
    const int p = i >> 14, xid = i & 16383;
    const float* src = (reg == 0 ? w1a : reg == 1 ? w3a : w3b) + (size_t)i * 3;
    const size_t base = (reg == 0) ? 0 : (reg == 1) ? 786432 : 1835008;
    #pragma unroll
    for (int t = 0; t < 3; ++t)
      out[base + (size_t)(p * 3 + t) * 16384 + xid] = f2bf(src[t]);
  } else {                             // W1B passthrough: 262144 elems
    const int i = (b - 3072) * 256 + tid;
    out[1572864 + i] = f2bf(w1b[i]);
  }
}

// ===================== MFMA main kernel =====================
// FINAL (r11 configuration — empirical floor of this structure):
// 118.9us bench / 140.4us rocprof, 11.9x over the round-1 vector baseline.
// Evidence ledger for why each knob is where it is:
//  * 16x16x32 MFMA, 8 indep acc chains in phase A — r10's 32x32 form (2
//    chains, back-to-back dependent MFMAs) was −30% instructions but +37%
//    time: the kernel is dependency-latency bound, ILP matters most.
//  * #pragma unroll 2 on the ks loop — unroll 8 (r12) regressed 24%:
//    I-cache/scheduling-window pressure, no added prefetch (VGPR stayed 84).
//  * 3 blocks/CU (51.7 KB LDS) — occupancy 2/3/4 blocks/CU all measured
//    within noise (r3/r8/r9); extra waves don't help a barrier-phased
//    latency-bound kernel, so don't pay restructuring costs for them.
//  * XOR-swizzle LDS — padded-stride (r9) moved bank-conflict counter UP
//    and perf nowhere; both layouts near the b128 structural minimum.
//  * Separate B1/B3 accumulators (r11) + sum3 reuse — neutral-to-small-win,
//    kept (no cost).
//  * __launch_bounds__(256,2): this compiler's effective VGPR cap = 256/arg2
//    (calibrated r4-r8: (512,6)->40, (512,3)->80, (256,4)->64, (256,2)->128).
//    Any tighter cap spills (100-290 MB scratch traffic, WRITE_SIZE blowup).
//  XT[r][c]: r = s+2, rows 0..67, 256 cols, XOR-swizzled, pad rows 0,1,66,67.
//  HT[r][h]: r = s+1, rows 0..65, 64 cols, pad rows 0,65.
#define XROWS 68
#define HROWS 66

__device__ __forceinline__ int xsw(int r, int c) { return (r * 256 + c) ^ ((r & 7) << 3); }
__device__ __forceinline__ int hsw(int r, int c) { return (r * 64 + c) ^ ((r & 7) << 3); }

__global__ __launch_bounds__(256, 2) void tfa_mfma(
    const float* __restrict__ x,
    const u16* __restrict__ wsb,
    float* __restrict__ out)
{
  const u16* W1A = wsb;                 // [p][t][h][c]  786432
  const u16* W3A = wsb + 786432;        // [p][t][h][c]  786432
  const u16* W1B = wsb + 1572864;       // [p][c][h]     262144
  const u16* W3B = wsb + 1835008;       // [p][t][c][h]  786432

  __shared__ __attribute__((aligned(16))) u16 xt[XROWS * 256];   // 34816 B
  __shared__ __attribute__((aligned(16))) u16 ht1[HROWS * 64];   //  8448 B
  __shared__ __attribute__((aligned(16))) u16 ht3[HROWS * 64];   //  8448 B

  const int tid = threadIdx.x;
  const int bid = blockIdx.x;          // p*NB + n
  const int p = bid >> 7;
  const int lane = tid & 63;
  const int w = tid >> 6;              // wave id 0..3

  // ---- zero the pad rows ----
  if (tid < 128) {
    const int rr4 = (tid >> 5);
    const int r = (rr4 == 0) ? 0 : (rr4 == 1) ? 1 : (rr4 == 2) ? 66 : 67;
    const int c = (tid & 31) * 8;
    *(ushort8*)&xt[xsw(r, c)] = (ushort8)0;
  } else if (tid < 160) {
    const int t2 = tid - 128;          // bit4=buffer, bit3=row, bits0-2=col chunk
    const int r = (t2 & 8) ? 65 : 0;
    const int c = (t2 & 7) * 8;
    u16* b = (t2 & 16) ? ht3 : ht1;
    *(ushort8*)&b[hsw(r, c)] = (ushort8)0;
  }

  // ---- stage x -> XT (transposed, bf16, swizzled); lane = s, wave: 64 c ----
  {
    const float* xb = x + (size_t)bid * (CH * SL);
    const int s = lane;
    const int r = s + 2;
    #pragma unroll
    for (int j = 0; j < 8; ++j) {
      const int c0 = w * 64 + j * 8;
      union { ushort8 v; unsigned u[4]; } ov;
      #pragma unroll
      for (int k = 0; k < 4; ++k) {
        const float fa = xb[(c0 + 2 * k) * 64 + s];
        const float fb = xb[(c0 + 2 * k + 1) * 64 + s];
        ov.u[k] = pk2bf(fa, fb);
      }
      *(ushort8*)&xt[xsw(r, c0)] = ov.v;
    }
  }
  __syncthreads();

  // ---- phase A: conv1 both branches; wave owns h-tile [w*16, w*16+16) ----
  // 8 independent accumulator chains; unroll 2 = measured optimum.
  {
    const int hm = lane & 15;
    const int kg = lane >> 4;
    const int h = w * 16 + hm;
    f32x4 acc1[4], acc3[4];
    #pragma unroll
    for (int nt = 0; nt < 4; ++nt) { acc1[nt] = (f32x4)0.f; acc3[nt] = (f32x4)0.f; }

    #pragma unroll 2
    for (int ks = 0; ks < 8; ++ks) {
      const int kc = ks * 32 + kg * 8;
      short8v a1[3], a3[3];
      #pragma unroll
      for (int t = 0; t < 3; ++t) {
        a1[t] = *(const short8v*)&W1A[(size_t)((p * 3 + t) * 64 + h) * 256 + kc];
        a3[t] = *(const short8v*)&W3A[(size_t)((p * 3 + t) * 64 + h) * 256 + kc];
      }
      #pragma unroll
      for (int nt = 0; nt < 4; ++nt) {
        const int s = nt * 16 + hm;    // B-frag n index
        #pragma unroll
        for (int t = 0; t < 3; ++t) {
          const int r = s + t + 1;     // tap s+(t-1) -> XT row; pads give zeros
          const short8v b = *(const short8v*)&xt[xsw(r, kc)];
          acc1[nt] = __builtin_amdgcn_mfma_f32_16x16x32_bf16(a1[t], b, acc1[nt], 0, 0, 0);
          acc3[nt] = __builtin_amdgcn_mfma_f32_16x16x32_bf16(a3[t], b, acc3[nt], 0, 0, 0);
        }
      }
    }

    // epilogue: LeakyReLU -> bf16 -> HT[s][h]
    const int hc = w * 16 + kg * 4;
    #pragma unroll
    for (int nt = 0; nt < 4; ++nt) {
      const int s = nt * 16 + hm;
      const int r = s + 1;
      float v1[4], v3[4];
      #pragma unroll
      for (int q = 0; q < 4; ++q) {
        const float a = acc1[nt][q]; v1[q] = a >= 0.f ? a : 0.01f * a;
        const float bq = acc3[nt][q]; v3[q] = bq >= 0.f ? bq : 0.01f * bq;
      }
      union { ushort4v v; u32 u[2]; } o1, o3;
      o1.u[0] = pk2bf(v1[0], v1[1]); o1.u[1] = pk2bf(v1[2], v1[3]);
      o3.u[0] = pk2bf(v3[0], v3[1]); o3.u[1] = pk2bf(v3[2], v3[3]);
      *(ushort4v*)&ht1[hsw(r, hc)] = o1.v;
      *(ushort4v*)&ht3[hsw(r, hc)] = o3.v;
    }
  }
  __syncthreads();

  // ---- phase B: conv2 both branches + gates + pools + max over s ----
  // wave w owns c in [w*64, w*64+64), in mt-halves. Separate B1/B3 accs
  // so g1p's trans ops can overlap B3's MFMAs.
  {
    const int cm = lane & 15;
    const int kg = lane >> 4;

    #pragma unroll
    for (int half = 0; half < 2; ++half) {
      const int mtb = half * 2;
      f32x4 acc1b[2][4], acc3b[2][4];
      #pragma unroll
      for (int mt = 0; mt < 2; ++mt)
        #pragma unroll
        for (int nt = 0; nt < 4; ++nt) { acc1b[mt][nt] = (f32x4)0.f; acc3b[mt][nt] = (f32x4)0.f; }

      // branch 1: K=64h, k1 conv (no shift)
      #pragma unroll
      for (int ks = 0; ks < 2; ++ks) {
        const int kh = ks * 32 + kg * 8;
        short8v a[2];
        #pragma unroll
        for (int mt = 0; mt < 2; ++mt) {
          const int c = w * 64 + (mtb + mt) * 16 + cm;
          a[mt] = *(const short8v*)&W1B[((size_t)p * 256 + c) * 64 + kh];
        }
        #pragma unroll
        for (int nt = 0; nt < 4; ++nt) {
          const int s = nt * 16 + cm;
          const short8v b = *(const short8v*)&ht1[hsw(s + 1, kh)];
          #pragma unroll
          for (int mt = 0; mt < 2; ++mt)
            acc1b[mt][nt] = __builtin_amdgcn_mfma_f32_16x16x32_bf16(a[mt], b, acc1b[mt][nt], 0, 0, 0);
        }
      }

      // gates g1 = sigmoid(L1), packed bf16 pairs (independent of acc3b)
      unsigned g1p[2][4][2];
      #pragma unroll
      for (int mt = 0; mt < 2; ++mt)
        #pragma unroll
        for (int nt = 0; nt < 4; ++nt) {
          #pragma unroll
          for (int j = 0; j < 2; ++j) {
            const float ga = 1.f / (1.f + __expf(-acc1b[mt][nt][2 * j]));
            const float gb = 1.f / (1.f + __expf(-acc1b[mt][nt][2 * j + 1]));
            g1p[mt][nt][j] = pk2bf(ga, gb);
          }
        }

      // branch 3: 3 tap-GEMMs, K=64h each, B rows shifted (pads give zeros)
      #pragma unroll
      for (int ks = 0; ks < 2; ++ks) {
        const int kh = ks * 32 + kg * 8;
        #pragma unroll
        for (int t = 0; t < 3; ++t) {
          short8v a[2];
          #pragma unroll
          for (int mt = 0; mt < 2; ++mt) {
            const int c = w * 64 + (mtb + mt) * 16 + cm;
            a[mt] = *(const short8v*)&W3B[(size_t)((p * 3 + t) * 256 + c) * 64 + kh];
          }
          #pragma unroll
          for (int nt = 0; nt < 4; ++nt) {
            const int s = nt * 16 + cm;
            const short8v b = *(const short8v*)&ht3[hsw(s + t, kh)];  // s+(t-1)+1
            #pragma unroll
            for (int mt = 0; mt < 2; ++mt)
              acc3b[mt][nt] = __builtin_amdgcn_mfma_f32_16x16x32_bf16(a[mt], b, acc3b[mt][nt], 0, 0, 0);
          }
        }
      }

      // epilogue: pools from XT, gates, fused max over s
      #pragma unroll
      for (int mt = 0; mt < 2; ++mt) {
        const int c4 = w * 64 + (mtb + mt) * 16 + kg * 4;   // 4 consecutive c
        float fmx0 = -INFINITY, fmx1 = -INFINITY, fmx2 = -INFINITY, fmx3 = -INFINITY;
        #pragma unroll
        for (int nt = 0; nt < 4; ++nt) {
          const int s = nt * 16 + cm;               // D col: global s
          const ushort4v vm2 = *(const ushort4v*)&xt[xsw(s,     c4)];
          const ushort4v vm1 = *(const ushort4v*)&xt[xsw(s + 1, c4)];
          const ushort4v v0  = *(const ushort4v*)&xt[xsw(s + 2, c4)];
          const ushort4v vp1 = *(const ushort4v*)&xt[xsw(s + 3, c4)];
          const ushort4v vp2 = *(const ushort4v*)&xt[xsw(s + 4, c4)];
          const float NI = -INFINITY;
          float ft[4];
          #pragma unroll
          for (int q = 0; q < 4; ++q) {
            const float xm2 = bf2f(vm2[q]), xm1 = bf2f(vm1[q]), x0 = bf2f(v0[q]);
            const float xp1 = bf2f(vp1[q]), xp2 = bf2f(vp2[q]);
            const float mx3 = fmaxf(x0, fmaxf(s >= 1 ? xm1 : NI, s <= 62 ? xp1 : NI));
            const float mx5 = fmaxf(mx3, fmaxf(s >= 2 ? xm2 : NI, s <= 61 ? xp2 : NI));
            const float sum3 = xm1 + x0 + xp1;           // pads are zero
            const float av3 = sum3 * (1.f / 3.f);
            const float av5 = (sum3 + xm2 + xp2) * 0.2f; // sum3 reuse
            const float g1 = bf2f((u16)(g1p[mt][nt][q >> 1] >> ((q & 1) * 16)));
            const float g3 = 1.f / (1.f + __expf(-acc3b[mt][nt][q]));
            ft[q] = (av3 + mx3) * g1 + (av5 + mx5) * g3;
          }
          fmx0 = fmaxf(fmx0, ft[0]); fmx1 = fmaxf(fmx1, ft[1]);
          fmx2 = fmaxf(fmx2, ft[2]); fmx3 = fmaxf(fmx3, ft[3]);
        }
        // reduce max across the 16 lanes of each row-group
        #pragma unroll
        for (int off = 1; off < 16; off <<= 1) {
          fmx0 = fmaxf(fmx0, __shfl_xor(fmx0, off));
          fmx1 = fmaxf(fmx1, __shfl_xor(fmx1, off));
          fmx2 = fmaxf(fmx2, __shfl_xor(fmx2, off));
          fmx3 = fmaxf(fmx3, __shfl_xor(fmx3, off));
        }
        if (cm == 0) {
          float4 o; o.x = fmx0; o.y = fmx1; o.z = fmx2; o.w = fmx3;
          *(float4*)&out[(size_t)bid * 256 + c4] = o;
        }
      }
    }
  }
}

// ===================== fallback vector kernel (round-1, correct) =====================
#define XROW 72
#define HROW 72

__global__ __launch_bounds__(256, 2) void tfa_kernel(
    const float* __restrict__ x,
    const float* __restrict__ w1a,
    const float* __restrict__ w1b,
    const float* __restrict__ w3a,
    const float* __restrict__ w3b,
    float* __restrict__ out)
{
  __shared__ __attribute__((aligned(16))) u16 x_s[8 + CH * XROW];
  __shared__ __attribute__((aligned(16))) u16 h1_s[8 + HIDN * HROW];
  __shared__ __attribute__((aligned(16))) u16 h3_s[8 + HIDN * HROW];

  const int tid = threadIdx.x;
  const int bid = blockIdx.x;
  const int p = bid >> 7;

  {
    const ushort8 z = {0, 0, 0, 0, 0, 0, 0, 0};
    for (int i = tid; i < 257; i += 256) {
      u16* dst = (i == 0) ? &x_s[0] : &x_s[8 + (i - 1) * XROW + 64];
      *(ushort8*)dst = z;
    }
    if (tid < 65) {
      u16* d1 = (tid == 0) ? &h1_s[0] : &h1_s[8 + (tid - 1) * HROW + 64];
      *(ushort8*)d1 = z;
      u16* d3 = (tid == 0) ? &h3_s[0] : &h3_s[8 + (tid - 1) * HROW + 64];
      *(ushort8*)d3 = z;
    }
  }

  const float* xblk = x + (size_t)bid * (CH * SL);
  #pragma unroll
  for (int j = 0; j < 16; ++j) {
    const int g = tid + 256 * j;
    const float4 v = ((const float4*)xblk)[g];
    const int c = g >> 4, s4 = g & 15;
    ushort4v o;
    o[0] = f2bf(v.x); o[1] = f2bf(v.y); o[2] = f2bf(v.z); o[3] = f2bf(v.w);
    *(ushort4v*)&x_s[8 + c * XROW + s4 * 4] = o;
  }
  __syncthreads();

  {
    const int h = tid >> 2;
    const int sg = tid & 3;
    const int sb = sg << 4;
    float acc1[16], acc3[16];
    #pragma unroll
    for (int i = 0; i < 16; ++i) { acc1[i] = 0.f; acc3[i] = 0.f; }

    const float* w1a_p = w1a + ((size_t)p * HIDN + h) * (CH * 3);
    const float* w3a_p = w3a + ((size_t)p * HIDN + h) * (CH * 3);

    for (int c4 = 0; c4 < CH; c4 += 4) {
      const float4 a0v = *(const float4*)&w1a_p[c4 * 3];
      const float4 a1v = *(const float4*)&w1a_p[c4 * 3 + 4];
      const float4 a2v = *(const float4*)&w1a_p[c4 * 3 + 8];
      const float4 b0v = *(const float4*)&w3a_p[c4 * 3];
      const float4 b1v = *(const float4*)&w3a_p[c4 * 3 + 4];
      const float4 b2v = *(const float4*)&w3a_p[c4 * 3 + 8];
      float wa[12], wb[12];
      wa[0]=a0v.x; wa[1]=a0v.y; wa[2]=a0v.z; wa[3]=a0v.w;
      wa[4]=a1v.x; wa[5]=a1v.y; wa[6]=a1v.z; wa[7]=a1v.w;
      wa[8]=a2v.x; wa[9]=a2v.y; wa[10]=a2v.z; wa[11]=a2v.w;
      wb[0]=b0v.x; wb[1]=b0v.y; wb[2]=b0v.z; wb[3]=b0v.w;
      wb[4]=b1v.x; wb[5]=b1v.y; wb[6]=b1v.z; wb[7]=b1v.w;
      wb[8]=b2v.x; wb[9]=b2v.y; wb[10]=b2v.z; wb[11]=b2v.w;

      #pragma unroll
      for (int cc = 0; cc < 4; ++cc) {
        const int c = c4 + cc;
        const ushort8 w0v = *(const ushort8*)&x_s[c * XROW + sb];
        const ushort8 w1v = *(const ushort8*)&x_s[c * XROW + sb + 8];
        const ushort8 w2v = *(const ushort8*)&x_s[c * XROW + sb + 16];
        const ushort8 w3v = *(const ushort8*)&x_s[c * XROW + sb + 24];
        float xf[19];
        xf[0] = bf2f(w0v[7]);
        #pragma unroll
        for (int d = 0; d < 8; ++d) xf[1 + d] = bf2f(w1v[d]);
        #pragma unroll
        for (int d = 0; d < 8; ++d) xf[9 + d] = bf2f(w2v[d]);
        xf[17] = bf2f(w3v[0]);
        xf[18] = bf2f(w3v[1]);

        const float a0 = wa[cc * 3], a1 = wa[cc * 3 + 1], a2 = wa[cc * 3 + 2];
        const float b0 = wb[cc * 3], b1 = wb[cc * 3 + 1], b2 = wb[cc * 3 + 2];
        #pragma unroll
        for (int i = 0; i < 16; ++i) {
          const float xm = xf[i], x0 = xf[i + 1], xp = xf[i + 2];
          acc1[i] = fmaf(a0, xm, fmaf(a1, x0, fmaf(a2, xp, acc1[i])));
          acc3[i] = fmaf(b0, xm, fmaf(b1, x0, fmaf(b2, xp, acc3[i])));
        }
      }
    }

    ushort8 o1a, o1b, o3a, o3b;
    #pragma unroll
    for (int i = 0; i < 8; ++i) {
      float v1 = acc1[i];     v1 = v1 >= 0.f ? v1 : 0.01f * v1;
      float v3 = acc3[i];     v3 = v3 >= 0.f ? v3 : 0.01f * v3;
      o1a[i] = f2bf(v1); o3a[i] = f2bf(v3);
      float u1 = acc1[i + 8]; u1 = u1 >= 0.f ? u1 : 0.01f * u1;
      float u3 = acc3[i + 8]; u3 = u3 >= 0.f ? u3 : 0.01f * u3;
      o1b[i] = f2bf(u1); o3b[i] = f2bf(u3);
    }
    *(ushort8*)&h1_s[8 + h * HROW + sb]     = o1a;
    *(ushort8*)&h1_s[8 + h * HROW + sb + 8] = o1b;
    *(ushort8*)&h3_s[8 + h * HROW + sb]     = o3a;
    *(ushort8*)&h3_s[8 + h * HROW + sb + 8] = o3b;
  }
  __syncthreads();

  {
    const int lane = tid & 63;
    const int wid = __builtin_amdgcn_readfirstlane(tid >> 6);
    const int s = lane;
    const float* w1b_p = w1b + (size_t)p * (CH * HIDN);
    const float* w3b_p = w3b + (size_t)p * (CH * HIDN * 3);
    float* outp = out + (size_t)bid * CH;

    for (int q = 0; q < 16; ++q) {
      const int c0 = wid * 64 + q * 4;
      float l1[4] = {0.f, 0.f, 0.f, 0.f};
      float l3[4] = {0.f, 0.f, 0.f, 0.f};

      for (int h4 = 0; h4 < HIDN; h4 += 4) {
        float h1v[4], h3a[4], h3b[4], h3c[4];
        #pragma unroll
        for (int u = 0; u < 4; ++u) {
          const int hh = h4 + u;
          h1v[u] = bf2f(h1_s[8 + hh * HROW + s]);
          h3a[u] = bf2f(h3_s[7 + hh * HROW + s]);
          h3b[u] = bf2f(h3_s[8 + hh * HROW + s]);
          h3c[u] = bf2f(h3_s[9 + hh * HROW + s]);
        }
        #pragma unroll
        for (int j = 0; j < 4; ++j) {
          const int c = c0 + j;
          const float4 wv  = *(const float4*)&w1b_p[c * HIDN + h4];
          const float* w3  = &w3b_p[(size_t)(c * HIDN + h4) * 3];
          const float4 w30 = *(const float4*)w3;
          const float4 w31 = *(const float4*)(w3 + 4);
          const float4 w32 = *(const float4*)(w3 + 8);
          float ww[12];
          ww[0]=w30.x; ww[1]=w30.y; ww[2]=w30.z; ww[3]=w30.w;
          ww[4]=w31.x; ww[5]=w31.y; ww[6]=w31.z; ww[7]=w31.w;
          ww[8]=w32.x; ww[9]=w32.y; ww[10]=w32.z; ww[11]=w32.w;
          l1[j] = fmaf(wv.x, h1v[0], fmaf(wv.y, h1v[1],
                  fmaf(wv.z, h1v[2], fmaf(wv.w, h1v[3], l1[j]))));
          #pragma unroll
          for (int u = 0; u < 4; ++u) {
            l3[j] = fmaf(ww[u * 3], h3a[u],
                    fmaf(ww[u * 3 + 1], h3b[u],
                    fmaf(ww[u * 3 + 2], h3c[u], l3[j])));
          }
        }
      }

      #pragma unroll
      for (int j = 0; j < 4; ++j) {
        const int c = c0 + j;
        const u16* xr = &x_s[8 + c * XROW];
        const float xm2 = bf2f(xr[s - 2]);
        const float xm1 = bf2f(xr[s - 1]);
        const float x0  = bf2f(xr[s]);
        const float xp1 = bf2f(xr[s + 1]);
        const float xp2 = bf2f(xr[s + 2]);
        const float NI = -INFINITY;
        const float mx3 = fmaxf(x0, fmaxf(s >= 1 ? xm1 : NI, s <= 62 ? xp1 : NI));
        const float mx5 = fmaxf(mx3, fmaxf(s >= 2 ? xm2 : NI, s <= 61 ? xp2 : NI));
        const float av3 = (xm1 + x0 + xp1) * (1.f / 3.f);
        const float av5 = (xm2 + xm1 + x0 + xp1 + xp2) * 0.2f;
        const float sg1 = 1.f / (1.f + __expf(-l1[j]));
        const float sg3 = 1.f / (1.f + __expf(-l3[j]));
        float feat = (av3 + mx3) * sg1 + (av5 + mx5) * sg3;
        #pragma unroll
        for (int off = 32; off >= 1; off >>= 1)
          feat = fmaxf(feat, __shfl_xor(feat, off));
        if (lane == 0) outp[c] = feat;
      }
    }
  }
}

extern "C" void kernel_launch(void* const* d_in, const int* in_sizes, int n_in,
                              void* d_out, int out_size, void* d_ws, size_t ws_size,
                              hipStream_t stream) {
  (void)in_sizes; (void)n_in; (void)out_size;
  const float* x   = (const float*)d_in[0];
  const float* w1a = (const float*)d_in[1];
  const float* w1b = (const float*)d_in[2];
  const float* w3a = (const float*)d_in[3];
  const float* w3b = (const float*)d_in[4];
  float* out = (float*)d_out;

  const size_t WS_NEED = 2621440ull * 2ull;  // 5 MB of bf16 weights
  if (ws_size >= WS_NEED) {
    u16* wsb = (u16*)d_ws;
    cvt_all<<<4096, 256, 0, stream>>>(w1a, w3a, w1b, w3b, wsb);
    tfa_mfma<<<PARTS * NB, 256, 0, stream>>>(x, wsb, out);
  } else {
    tfa_kernel<<<PARTS * NB, 256, 0, stream>>>(x, w1a, w1b, w3a, w3b, out);
  }
}